// Round 15
// baseline (729.729 us; speedup 1.0000x reference)
//
#include <hip/hip_runtime.h>
#include <hip/hip_bf16.h>

#define N_LAYERS 4
#define D_MODEL  1024
#define D_INNER  2048
#define D_STATE  16
#define D_CONV   4
#define DT_RANK  64
#define BB       2
#define TT       1024
#define BT       (BB*TT)   // 2048 rows (b*T)

#define NCHUNK 32
#define SCTC   (TT/NCHUNK)   // 32 timesteps per chunk
#define TB     8             // scan load-batch depth

#define XP_KS  8             // x_proj K-split factor

typedef unsigned short ushort_t;
typedef __attribute__((ext_vector_type(8))) short short8;
typedef __attribute__((ext_vector_type(8))) unsigned short ushort8_t;
typedef __attribute__((ext_vector_type(4))) float f32x4;

__device__ __forceinline__ float sigmoidf_(float x){ return 1.f/(1.f+__expf(-x)); }
__device__ __forceinline__ float siluf_(float x){ return x*sigmoidf_(x); }
__device__ __forceinline__ float softplusf_(float x){ return fmaxf(x,0.f) + log1pf(__expf(-fabsf(x))); }
__device__ __forceinline__ ushort_t f2b(float f){
    unsigned int x = __builtin_bit_cast(unsigned int, f);
    unsigned int r = (x + 0x7fffu + ((x>>16)&1u)) >> 16;   // RNE
    return (ushort_t)r;
}
__device__ __forceinline__ float b2f(ushort_t u){
    unsigned int x = ((unsigned int)u) << 16;
    return __builtin_bit_cast(float, x);
}

#define GLOAD(g, l) __builtin_amdgcn_global_load_lds( \
    (const __attribute__((address_space(1))) void*)(g), \
    (__attribute__((address_space(3))) void*)(l), 16, 0, 0)

// One-shot conversion: x, in_w(all), out_w(all), dtp_w(all) -> bf16.
__global__ __launch_bounds__(256) void f2ball_k(
    const float* __restrict__ x, const float* __restrict__ in_w,
    const float* __restrict__ out_w, const float* __restrict__ dtp_w,
    ushort_t* __restrict__ xinb, ushort_t* __restrict__ winb,
    ushort_t* __restrict__ woutb, ushort_t* __restrict__ dtpb)
{
    const int n0 = (BT*1024)/8;
    const int n1 = (N_LAYERS*4096*1024)/8;
    const int n2 = (N_LAYERS*1024*2048)/8;
    int i = blockIdx.x*256 + threadIdx.x;
    const float4* src; ushort8_t* dst; int j;
    if (i < n0){ src=(const float4*)x; dst=(ushort8_t*)xinb; j=i; }
    else if (i < n0+n1){ src=(const float4*)in_w; dst=(ushort8_t*)winb; j=i-n0; }
    else if (i < n0+n1+n2){ src=(const float4*)out_w; dst=(ushort8_t*)woutb; j=i-n0-n1; }
    else { src=(const float4*)dtp_w; dst=(ushort8_t*)dtpb; j=i-n0-n1-n2; }
    float4 v0 = src[2*j], v1 = src[2*j+1];
    ushort8_t o;
    o[0]=f2b(v0.x); o[1]=f2b(v0.y); o[2]=f2b(v0.z); o[3]=f2b(v0.w);
    o[4]=f2b(v1.x); o[5]=f2b(v1.y); o[6]=f2b(v1.z); o[7]=f2b(v1.w);
    dst[j] = o;
}

// in_proj GEMM: outb[M][N](bf16) = A[M][K] @ W[N][K]^T. 128x128 tile, BK=32,
// 512 thr = 8 waves (2x4), wave = 64x32 via 4x2 frags. Depth-3 pipeline,
// 4 LDS buffers, vmcnt(4), setprio around MFMA. XCD rect swizzle.
__global__ __launch_bounds__(512) void gemm_ip(
    const ushort_t* __restrict__ A, const ushort_t* __restrict__ W,
    int M, int N, int K, ushort_t* __restrict__ outb,
    int RM, int RN, int XN)
{
    __shared__ ushort_t As[4][128*32];
    __shared__ ushort_t Ws[4][128*32];
    const int tid  = threadIdx.x;
    const int lane = tid & 63;
    const int wv   = tid >> 6;
    const int wm0  = (wv>>2)*64, wn0 = (wv&3)*32;

    const int bid = blockIdx.x;
    const int xcd = bid & 7, bi = bid >> 3;
    const int xm = xcd / XN, xn = xcd - xm*XN;
    const int m0 = (xm*RM + bi/RN)*128;
    const int n0 = (xn*RN + bi - (bi/RN)*RN)*128;

    const int r0 = tid>>2, ch = tid&3;

    f32x4 acc[4][2];
    #pragma unroll
    for (int i=0;i<4;++i)
        #pragma unroll
        for (int j=0;j<2;++j) acc[i][j] = (f32x4){0.f,0.f,0.f,0.f};

    const int row_a = lane & 15, kc = (lane>>4)*8;
    const ushort_t* gA = A + (size_t)(m0+r0)*K + ch*8;
    const ushort_t* gW = W + (size_t)(n0+r0)*K + ch*8;

#define STAGE(KT, BUF) { \
    GLOAD(gA + (KT)*32, (char*)&As[BUF][0] + tid*16); \
    GLOAD(gW + (KT)*32, (char*)&Ws[BUF][0] + tid*16); }

#define COMPUTE(BUF) { \
    short8 af[4], bf[2]; \
    _Pragma("unroll") \
    for (int i=0;i<4;++i) af[i] = *(const short8*)&As[BUF][(wm0 + i*16 + row_a)*32 + kc]; \
    _Pragma("unroll") \
    for (int j=0;j<2;++j) bf[j] = *(const short8*)&Ws[BUF][(wn0 + j*16 + row_a)*32 + kc]; \
    __builtin_amdgcn_s_setprio(1); \
    _Pragma("unroll") \
    for (int i=0;i<4;++i) \
        _Pragma("unroll") \
        for (int j=0;j<2;++j) \
            acc[i][j] = __builtin_amdgcn_mfma_f32_16x16x32_bf16(af[i], bf[j], acc[i][j], 0,0,0); \
    __builtin_amdgcn_s_setprio(0); }

    const int nt = K >> 5;
    STAGE(0, 0); STAGE(1, 1); STAGE(2, 2);
    for (int t = 0; t < nt-3; ++t){
        asm volatile("s_waitcnt vmcnt(4)" ::: "memory");
        asm volatile("s_barrier" ::: "memory");
        STAGE(t+3, (t+3)&3);
        COMPUTE(t&3);
    }
    asm volatile("s_waitcnt vmcnt(4)" ::: "memory");
    asm volatile("s_barrier" ::: "memory");
    COMPUTE((nt-3)&3);
    asm volatile("s_waitcnt vmcnt(2)" ::: "memory");
    asm volatile("s_barrier" ::: "memory");
    COMPUTE((nt-2)&3);
    asm volatile("s_waitcnt vmcnt(0)" ::: "memory");
    asm volatile("s_barrier" ::: "memory");
    COMPUTE((nt-1)&3);
#undef STAGE
#undef COMPUTE

    const int crow = (lane>>4)*4, ccol = lane & 15;
    #pragma unroll
    for (int i=0;i<4;++i){
        #pragma unroll
        for (int j=0;j<2;++j){
            #pragma unroll
            for (int r=0;r<4;++r){
                int m = m0 + wm0 + i*16 + crow + r;
                int n = n0 + wn0 + j*16 + ccol;
                outb[(size_t)m*N + n] = f2b(acc[i][j][r]);
            }
        }
    }
}

// out_proj GEMM: C = ys @ W^T + res (fp32), bf16 copy to outb. 64x64 tile,
// 4 waves of 32x32. Step-paired: 6 LDS buffers, 2 BK=32 steps per barrier,
// vmcnt(4), setprio. XCD rect swizzle.
__global__ __launch_bounds__(256) void gemm_op(
    const ushort_t* __restrict__ A, const ushort_t* __restrict__ W,
    float* __restrict__ C, int M, int N, int K,
    const float* __restrict__ res, ushort_t* __restrict__ outb,
    int RM, int RN, int XN)
{
    __shared__ ushort_t As[6][64*32];
    __shared__ ushort_t Ws[6][64*32];
    const int tid  = threadIdx.x;
    const int lane = tid & 63;
    const int wv   = tid >> 6;
    const int wm0  = (wv>>1)*32, wn0 = (wv&1)*32;

    const int bid = blockIdx.x;
    const int xcd = bid & 7, bi = bid >> 3;
    const int xm = xcd / XN, xn = xcd - xm*XN;
    const int m0 = (xm*RM + bi/RN)*64;
    const int n0 = (xn*RN + bi - (bi/RN)*RN)*64;

    const int r0 = tid>>2, ch = tid&3;

    f32x4 acc[2][2];
    #pragma unroll
    for (int i=0;i<2;++i)
        #pragma unroll
        for (int j=0;j<2;++j) acc[i][j] = (f32x4){0.f,0.f,0.f,0.f};

    const int row_a = lane & 15, kc = (lane>>4)*8;
    const ushort_t* gA = A + (size_t)(m0+r0)*K + ch*8;
    const ushort_t* gW = W + (size_t)(n0+r0)*K + ch*8;

#define STAGE(KT, BUF) { \
    GLOAD(gA + (KT)*32, (char*)&As[BUF][0] + tid*16); \
    GLOAD(gW + (KT)*32, (char*)&Ws[BUF][0] + tid*16); }

#define COMPUTE(BUF) { \
    short8 af[2], bf[2]; \
    _Pragma("unroll") \
    for (int i=0;i<2;++i) af[i] = *(const short8*)&As[BUF][(wm0 + i*16 + row_a)*32 + kc]; \
    _Pragma("unroll") \
    for (int j=0;j<2;++j) bf[j] = *(const short8*)&Ws[BUF][(wn0 + j*16 + row_a)*32 + kc]; \
    _Pragma("unroll") \
    for (int i=0;i<2;++i) \
        _Pragma("unroll") \
        for (int j=0;j<2;++j) \
            acc[i][j] = __builtin_amdgcn_mfma_f32_16x16x32_bf16(af[i], bf[j], acc[i][j], 0,0,0); }

    const int np = K >> 6;            // step pairs (K=2048 -> 32)
    STAGE(0, 0); STAGE(1, 1);
    STAGE(2, 2); STAGE(3, 3);
    for (int p = 0; p < np-2; ++p){
        const int bA = (p%3)*2, bS = ((p+2)%3)*2;
        asm volatile("s_waitcnt vmcnt(4)" ::: "memory");
        asm volatile("s_barrier" ::: "memory");
        STAGE(2*p+4, bS); STAGE(2*p+5, bS+1);
        __builtin_amdgcn_s_setprio(1);
        COMPUTE(bA); COMPUTE(bA+1);
        __builtin_amdgcn_s_setprio(0);
    }
    {
        const int bA = ((np-2)%3)*2;
        asm volatile("s_waitcnt vmcnt(4)" ::: "memory");
        asm volatile("s_barrier" ::: "memory");
        COMPUTE(bA); COMPUTE(bA+1);
    }
    {
        const int bA = ((np-1)%3)*2;
        asm volatile("s_waitcnt vmcnt(0)" ::: "memory");
        asm volatile("s_barrier" ::: "memory");
        COMPUTE(bA); COMPUTE(bA+1);
    }
#undef STAGE
#undef COMPUTE

    const int crow = (lane>>4)*4, ccol = lane & 15;
    #pragma unroll
    for (int i=0;i<2;++i){
        #pragma unroll
        for (int j=0;j<2;++j){
            #pragma unroll
            for (int r=0;r<4;++r){
                int m = m0 + wm0 + i*16 + crow + r;
                int n = n0 + wn0 + j*16 + ccol;
                float v = acc[i][j][r] + res[(size_t)m*N + n];
                C[(size_t)m*N + n] = v;
                outb[(size_t)m*N + n] = f2b(v);
            }
        }
    }
}

// dt_proj bf16 MFMA: dtb[M][N](bf16) = softplus(A[M][64] @ W[N][64]^T + bias).
__global__ __launch_bounds__(256) void dt_mfma(
    const ushort_t* __restrict__ A, const ushort_t* __restrict__ W,
    const float* __restrict__ bias, ushort_t* __restrict__ dtb, int N)
{
    __shared__ ushort_t As[2][64*32];
    __shared__ ushort_t Ws[2][64*32];
    const int tid = threadIdx.x, lane = tid&63, wv = tid>>6;
    const int wm0 = (wv>>1)*32, wn0 = (wv&1)*32;
    const int m0 = blockIdx.y*64, n0 = blockIdx.x*64;
    const int r0 = tid>>2, ch = tid&3;
    const ushort_t* gA = A + (size_t)(m0+r0)*64 + ch*8;
    const ushort_t* gW = W + (size_t)(n0+r0)*64 + ch*8;
    GLOAD(gA,      (char*)&As[0][0] + tid*16);
    GLOAD(gW,      (char*)&Ws[0][0] + tid*16);
    GLOAD(gA + 32, (char*)&As[1][0] + tid*16);
    GLOAD(gW + 32, (char*)&Ws[1][0] + tid*16);

    f32x4 acc[2][2];
    #pragma unroll
    for (int i=0;i<2;++i)
        #pragma unroll
        for (int j=0;j<2;++j) acc[i][j] = (f32x4){0.f,0.f,0.f,0.f};

    asm volatile("s_waitcnt vmcnt(0)" ::: "memory");
    asm volatile("s_barrier" ::: "memory");
    const int row_a = lane&15, kc = (lane>>4)*8;
    #pragma unroll
    for (int buf=0; buf<2; ++buf){
        short8 af[2], bf[2];
        #pragma unroll
        for (int i=0;i<2;++i) af[i] = *(const short8*)&As[buf][(wm0 + i*16 + row_a)*32 + kc];
        #pragma unroll
        for (int j=0;j<2;++j) bf[j] = *(const short8*)&Ws[buf][(wn0 + j*16 + row_a)*32 + kc];
        #pragma unroll
        for (int i=0;i<2;++i)
            #pragma unroll
            for (int j=0;j<2;++j)
                acc[i][j] = __builtin_amdgcn_mfma_f32_16x16x32_bf16(af[i], bf[j], acc[i][j], 0,0,0);
    }

    const int crow = (lane>>4)*4, ccol = lane & 15;
    #pragma unroll
    for (int i=0;i<2;++i){
        #pragma unroll
        for (int j=0;j<2;++j){
            #pragma unroll
            for (int r=0;r<4;++r){
                int m = m0 + wm0 + i*16 + crow + r;
                int n = n0 + wn0 + j*16 + ccol;
                float v = softplusf_(acc[i][j][r] + bias[n]);
                dtb[(size_t)m*N + n] = f2b(v);
            }
        }
    }
}

// Split-K fp32 GEMM for x_proj with conv+SiLU fused via LDS halo tile.
// A[m][c] = silu(conv4(xzb[:, c]) + cb[c]) computed from a 67-row halo staged
// in LDS (3/64 extra reads, no per-thread redundancy). n0==0 blocks write
// ucb (bf16) through as a byproduct (each element exactly once).
// Grid (N/64=2, M/64=32, XP_KS).
__global__ __launch_bounds__(256) void gemm_sk_conv(
    const ushort_t* __restrict__ xzb, const float* __restrict__ cw,
    const float* __restrict__ cb,
    const float* __restrict__ W, int ldw,
    float* __restrict__ P, ushort_t* __restrict__ ucb,
    int M, int N, int K)
{
    __shared__ float As[16][68];
    __shared__ float Ws[16][68];
    __shared__ ushort_t xh[67][20];   // rows m0-3..m0+63, 16 chans, padded
    const int tid = threadIdx.x;
    const int tx = tid & 15, ty = tid >> 4;
    const int m0 = blockIdx.y * 64, n0 = blockIdx.x * 64;
    const int kbase = blockIdx.z * (K/XP_KS);
    const int lr = tid >> 2;
    const int lk = (tid & 3) << 2;
    const bool wr_uc = (blockIdx.x == 0);
    const int t = (m0 + lr) & (TT-1);
    float acc[4][4] = {{0.f}};

    for (int kk = 0; kk < K/XP_KS; kk += 16) {
        const int k0 = kbase + kk;
        float4 wvv = make_float4(0.f,0.f,0.f,0.f);
        if (n0 + lr < N) wvv = *(const float4*)(W + (size_t)(n0+lr)*ldw + k0 + lk);
        __syncthreads();                       // protect prev-iter LDS reads
        for (int s = tid; s < 268; s += 256){  // stage halo tile
            int r = s >> 2, cg = s & 3;
            int mrow = m0 + r - 3;
            ushort4 v; v.x=0; v.y=0; v.z=0; v.w=0;
            if (mrow >= 0) v = *(const ushort4*)(xzb + (size_t)mrow*4096 + k0 + cg*4);
            *(ushort4*)&xh[r][cg*4] = v;
        }
        __syncthreads();
        {
            float av[4];
            #pragma unroll
            for (int jj=0;jj<4;++jj){
                int cc = lk + jj;
                float4 w4 = *(const float4*)(cw + (size_t)(k0+cc)*4);
                float a = cb[k0+cc];
                if (t >= 3) a = fmaf(b2f(xh[lr+0][cc]), w4.x, a);
                if (t >= 2) a = fmaf(b2f(xh[lr+1][cc]), w4.y, a);
                if (t >= 1) a = fmaf(b2f(xh[lr+2][cc]), w4.z, a);
                a = fmaf(b2f(xh[lr+3][cc]), w4.w, a);
                av[jj] = siluf_(a);
            }
            if (wr_uc){
                ushort4 uo;
                uo.x=f2b(av[0]); uo.y=f2b(av[1]); uo.z=f2b(av[2]); uo.w=f2b(av[3]);
                *(ushort4*)(ucb + (size_t)(m0+lr)*D_INNER + k0 + lk) = uo;
            }
            As[lk+0][lr]=av[0]; As[lk+1][lr]=av[1]; As[lk+2][lr]=av[2]; As[lk+3][lr]=av[3];
            Ws[lk+0][lr]=wvv.x; Ws[lk+1][lr]=wvv.y; Ws[lk+2][lr]=wvv.z; Ws[lk+3][lr]=wvv.w;
        }
        __syncthreads();
        #pragma unroll
        for (int k = 0; k < 16; ++k) {
            float4 a = *(const float4*)&As[k][ty<<2];
            float4 b = *(const float4*)&Ws[k][tx<<2];
            float a4[4] = {a.x,a.y,a.z,a.w};
            float b4[4] = {b.x,b.y,b.z,b.w};
            #pragma unroll
            for (int i=0;i<4;++i)
                #pragma unroll
                for (int j=0;j<4;++j)
                    acc[i][j] = fmaf(a4[i], b4[j], acc[i][j]);
        }
    }

    float* Pz = P + (size_t)blockIdx.z * M * 96;
    #pragma unroll
    for (int i=0;i<4;++i){
        int m = m0 + (ty<<2) + i;
        #pragma unroll
        for (int j=0;j<4;++j){
            int n = n0 + (tx<<2) + j;
            if (n < N) Pz[(size_t)m*96 + n] = acc[i][j];
        }
    }
}

// xdbl[g] = sum_ks P[ks][g]; also emit bf16 dt_r (cols<64) to dtrb[M][64].
__global__ __launch_bounds__(256) void sk_reduce(
    const float* __restrict__ P, float* __restrict__ outp,
    ushort_t* __restrict__ dtrb, int MN)
{
    int g = blockIdx.x*256 + threadIdx.x;
    float s = 0.f;
    #pragma unroll
    for (int ks=0; ks<XP_KS; ++ks) s += P[(size_t)ks*MN + g];
    outp[g] = s;
    int m = g / 96, c = g - m*96;
    if (c < 64) dtrb[(size_t)m*64 + c] = f2b(s);
}

// ---- Chunked selective scan (3 separate kernels), bf16 dt/u, TB batching. ----

__global__ __launch_bounds__(256) void scan_p1(
    const ushort_t* __restrict__ dt, const ushort_t* __restrict__ uc,
    const float* __restrict__ xdbl, const float* __restrict__ A_log,
    float* __restrict__ hpart, float* __restrict__ hdecay)
{
    const int tid = threadIdx.x;
    const int d = blockIdx.x*256 + tid;
    const int b = blockIdx.y;
    const int k = blockIdx.z;
    const int t0 = k*SCTC;
    float A[16];
    #pragma unroll
    for (int q=0;q<4;++q){
        float4 v = *(const float4*)(A_log + (size_t)d*16 + q*4);
        A[q*4+0]=-__expf(v.x); A[q*4+1]=-__expf(v.y);
        A[q*4+2]=-__expf(v.z); A[q*4+3]=-__expf(v.w);
    }
    float h[16];
    #pragma unroll
    for (int s=0;s<16;++s) h[s]=0.f;
    float sumdt = 0.f;
    const ushort_t* dtp = dt + ((size_t)b*TT + t0)*D_INNER + d;
    const ushort_t* ucp = uc + ((size_t)b*TT + t0)*D_INNER + d;
    const float* bcp = xdbl + ((size_t)b*TT + t0)*96 + 64;
    #pragma unroll
    for (int tb=0; tb<SCTC; tb+=TB){
        float dtv[TB], ur[TB];
        #pragma unroll
        for (int j=0;j<TB;++j){
            dtv[j] = b2f(dtp[(size_t)(tb+j)*D_INNER]);
            ur[j]  = b2f(ucp[(size_t)(tb+j)*D_INNER]);
        }
        #pragma unroll
        for (int j=0;j<TB;++j){
            const float* bc = bcp + (size_t)(tb+j)*96;
            float du = dtv[j]*ur[j];
            sumdt += dtv[j];
            #pragma unroll
            for (int s=0;s<16;++s)
                h[s] = fmaf(__expf(dtv[j]*A[s]), h[s], du*bc[s]);
        }
    }
    size_t base = ((size_t)(k*BB+b)*D_INNER + d)*16;
    float4* hp = (float4*)(hpart + base);
    float4* hd = (float4*)(hdecay + base);
    #pragma unroll
    for (int q=0;q<4;++q){
        hp[q] = make_float4(h[q*4],h[q*4+1],h[q*4+2],h[q*4+3]);
        hd[q] = make_float4(__expf(sumdt*A[q*4+0]),__expf(sumdt*A[q*4+1]),
                            __expf(sumdt*A[q*4+2]),__expf(sumdt*A[q*4+3]));
    }
}

__global__ __launch_bounds__(256) void scan_fix(
    const float* __restrict__ hpart, const float* __restrict__ hdecay,
    float* __restrict__ hstart)
{
    int g = blockIdx.x*256 + threadIdx.x;
    float h = 0.f;
    #pragma unroll
    for (int k=0;k<NCHUNK;++k){
        size_t idx = (size_t)k*(BB*D_INNER*16) + g;
        hstart[idx] = h;
        h = fmaf(hdecay[idx], h, hpart[idx]);
    }
}

__global__ __launch_bounds__(256) void scan_p3(
    const ushort_t* __restrict__ dt, const ushort_t* __restrict__ uc,
    const float* __restrict__ xdbl, const float* __restrict__ A_log,
    const ushort_t* __restrict__ xzb, const float* __restrict__ Dd,
    const float* __restrict__ hstart, ushort_t* __restrict__ ysb)
{
    const int tid = threadIdx.x;
    const int d = blockIdx.x*256 + tid;
    const int b = blockIdx.y;
    const int k = blockIdx.z;
    const int t0 = k*SCTC;
    float A[16];
    #pragma unroll
    for (int q=0;q<4;++q){
        float4 v = *(const float4*)(A_log + (size_t)d*16 + q*4);
        A[q*4+0]=-__expf(v.x); A[q*4+1]=-__expf(v.y);
        A[q*4+2]=-__expf(v.z); A[q*4+3]=-__expf(v.w);
    }
    float h[16];
    {
        const float4* hs = (const float4*)(hstart + ((size_t)(k*BB+b)*D_INNER + d)*16);
        #pragma unroll
        for (int q=0;q<4;++q){
            float4 v = hs[q];
            h[q*4+0]=v.x; h[q*4+1]=v.y; h[q*4+2]=v.z; h[q*4+3]=v.w;
        }
    }
    const float Ddc = Dd[d];
    const ushort_t* dtp = dt + ((size_t)b*TT + t0)*D_INNER + d;
    const ushort_t* ucp = uc + ((size_t)b*TT + t0)*D_INNER + d;
    const ushort_t* zp  = xzb + ((size_t)b*TT + t0)*4096 + 2048 + d;
    const float* bcp = xdbl + ((size_t)b*TT + t0)*96 + 64;
    ushort_t* yp = ysb + ((size_t)b*TT + t0)*D_INNER + d;
    #pragma unroll
    for (int tb=0; tb<SCTC; tb+=TB){
        float dtv[TB], ur[TB], zr[TB];
        #pragma unroll
        for (int j=0;j<TB;++j){
            dtv[j] = b2f(dtp[(size_t)(tb+j)*D_INNER]);
            ur[j]  = b2f(ucp[(size_t)(tb+j)*D_INNER]);
            zr[j]  = b2f(zp [(size_t)(tb+j)*4096]);
        }
        #pragma unroll
        for (int j=0;j<TB;++j){
            const float* bc = bcp + (size_t)(tb+j)*96;
            float du = dtv[j]*ur[j];
            float y0=0.f,y1=0.f,y2=0.f,y3=0.f;
            #pragma unroll
            for (int q=0;q<4;++q){
                h[q*4+0] = fmaf(__expf(dtv[j]*A[q*4+0]), h[q*4+0], du*bc[q*4+0]);
                h[q*4+1] = fmaf(__expf(dtv[j]*A[q*4+1]), h[q*4+1], du*bc[q*4+1]);
                h[q*4+2] = fmaf(__expf(dtv[j]*A[q*4+2]), h[q*4+2], du*bc[q*4+2]);
                h[q*4+3] = fmaf(__expf(dtv[j]*A[q*4+3]), h[q*4+3], du*bc[q*4+3]);
            }
            #pragma unroll
            for (int q=0;q<4;++q){
                y0 = fmaf(h[q*4+0], bc[16+q*4+0], y0);
                y1 = fmaf(h[q*4+1], bc[16+q*4+1], y1);
                y2 = fmaf(h[q*4+2], bc[16+q*4+2], y2);
                y3 = fmaf(h[q*4+3], bc[16+q*4+3], y3);
            }
            float y = (y0+y1)+(y2+y3);
            float yv = (y + ur[j]*Ddc) * siluf_(zr[j]);
            yp[(size_t)(tb+j)*D_INNER] = f2b(yv);
        }
    }
}

__global__ __launch_bounds__(256) void layernorm_k(
    const float* __restrict__ X, const float* __restrict__ w,
    const float* __restrict__ b, float* __restrict__ out)
{
    int row = blockIdx.x;
    int tid = threadIdx.x;
    const float* xr = X + (size_t)row*D_MODEL;
    float4 v = *(const float4*)(xr + tid*4);
    float s  = v.x+v.y+v.z+v.w;
    float ss = fmaf(v.x,v.x, fmaf(v.y,v.y, fmaf(v.z,v.z, v.w*v.w)));
    #pragma unroll
    for (int off=32; off>0; off>>=1){
        s  += __shfl_down(s, off, 64);
        ss += __shfl_down(ss, off, 64);
    }
    __shared__ float red[8];
    int wid = tid>>6, lane = tid&63;
    if (lane==0){ red[wid]=s; red[4+wid]=ss; }
    __syncthreads();
    if (tid==0){
        float S  = red[0]+red[1]+red[2]+red[3];
        float SS = red[4]+red[5]+red[6]+red[7];
        float mu = S*(1.f/D_MODEL);
        float var = SS*(1.f/D_MODEL) - mu*mu;
        red[0]=mu; red[1]=rsqrtf(var + 1e-5f);
    }
    __syncthreads();
    float mu=red[0], rs=red[1];
    float4 wv = *(const float4*)(w + tid*4);
    float4 bv = *(const float4*)(b + tid*4);
    float4 o;
    o.x = fmaf((v.x-mu)*rs, wv.x, bv.x);
    o.y = fmaf((v.y-mu)*rs, wv.y, bv.y);
    o.z = fmaf((v.z-mu)*rs, wv.z, bv.z);
    o.w = fmaf((v.w-mu)*rs, wv.w, bv.w);
    *(float4*)(out + (size_t)row*D_MODEL + tid*4) = o;
}

extern "C" void kernel_launch(void* const* d_in, const int* in_sizes, int n_in,
                              void* d_out, int out_size, void* d_ws, size_t ws_size,
                              hipStream_t stream) {
    (void)in_sizes; (void)n_in; (void)out_size; (void)ws_size;
    const float* x      = (const float*)d_in[0];
    const float* in_w   = (const float*)d_in[1];
    const float* conv_w = (const float*)d_in[2];
    const float* conv_b = (const float*)d_in[3];
    const float* xp_w   = (const float*)d_in[4];
    const float* dtp_w  = (const float*)d_in[5];
    const float* dtp_b  = (const float*)d_in[6];
    const float* A_log  = (const float*)d_in[7];
    const float* Dd     = (const float*)d_in[8];
    const float* out_w  = (const float*)d_in[9];
    const float* nw     = (const float*)d_in[10];
    const float* nb     = (const float*)d_in[11];
    float* out = (float*)d_out;

    char* p = (char*)d_ws;
    ushort_t* xzb  = (ushort_t*)p; p += (size_t)BT*4096*2;     // 16 MB
    ushort_t* ucb  = (ushort_t*)p; p += (size_t)BT*2048*2;     // 8 MB
    float* xdbl    = (float*)p;  p += (size_t)BT*96*4;         // 768 KB
    ushort_t* dtrb = (ushort_t*)p; p += (size_t)BT*64*2;       // 256 KB
    ushort_t* dtbb = (ushort_t*)p; p += (size_t)BT*2048*2;     // 8 MB
    float* xcur    = (float*)p;  p += (size_t)BT*1024*4;       // 8 MB
    ushort_t* xinb = (ushort_t*)p; p += (size_t)BT*1024*2;     // 4 MB
    ushort_t* ysb  = (ushort_t*)p; p += (size_t)BT*2048*2;     // 8 MB
    ushort_t* winb = (ushort_t*)p; p += (size_t)N_LAYERS*4096*1024*2;  // 32 MB
    ushort_t* woutb= (ushort_t*)p; p += (size_t)N_LAYERS*1024*2048*2;  // 16 MB
    ushort_t* dtpb = (ushort_t*)p; p += (size_t)N_LAYERS*2048*64*2;    // 1 MB
    float* hpart   = (float*)p;  p += (size_t)NCHUNK*BB*D_INNER*16*4;  // 8 MB
    float* hdecay  = (float*)p;  p += (size_t)NCHUNK*BB*D_INNER*16*4;  // 8 MB
    float* hstart  = (float*)p;  p += (size_t)NCHUNK*BB*D_INNER*16*4;  // 8 MB
    // pbuf (x_proj split-K partials, 6.3 MB) aliases hpart: consumed by
    // sk_reduce before scan_p1 writes hpart.
    float* pbuf    = hpart;

    // One-time conversions: x + all layers' weights, single launch.
    f2ball_k<<<(BT*1024 + N_LAYERS*(4096*1024 + 1024*2048 + 2048*64))/2048,
               256,0,stream>>>(x, in_w, out_w, dtp_w, xinb, winb, woutb, dtpb);

    for (int i = 0; i < N_LAYERS; ++i){
        const float* xin = (i==0) ? x : xcur;
        const float* cw = conv_w + (size_t)i*D_INNER*D_CONV;
        const float* cb = conv_b + (size_t)i*D_INNER;
        // xz = xin @ in_w^T (2048x4096 K=1024) -> bf16 xzb.
        gemm_ip<<<512,512,0,stream>>>(
            xinb, winb + (size_t)i*4096*1024, BT, 4096, D_MODEL, xzb, 8, 8, 4);
        // x_dbl partials = conv_silu(xzb) @ xp_w^T, split-K; conv via LDS halo;
        // n0==0 blocks also write ucb (bf16) through.
        gemm_sk_conv<<<dim3(2,32,XP_KS),256,0,stream>>>(
            xzb, cw, cb, xp_w + (size_t)i*96*D_INNER, D_INNER,
            pbuf, ucb, BT, 96, D_INNER);
        sk_reduce<<<(BT*96)/256,256,0,stream>>>(pbuf, xdbl, dtrb, BT*96);
        // dt = softplus(dt_r @ dtp_w^T + dtp_b) -> bf16, MFMA (K=64)
        dt_mfma<<<dim3(D_INNER/64, BT/64),256,0,stream>>>(
            dtrb, dtpb + (size_t)i*2048*64, dtp_b + (size_t)i*D_INNER, dtbb, D_INNER);
        // chunked selective scan (batched loads) + fused (y+u*D)*silu(z) -> bf16
        scan_p1<<<dim3(D_INNER/256, BB, NCHUNK),256,0,stream>>>(
            dtbb, ucb, xdbl, A_log + (size_t)i*D_INNER*D_STATE, hpart, hdecay);
        scan_fix<<<(BB*D_INNER*16)/256,256,0,stream>>>(hpart, hdecay, hstart);
        scan_p3<<<dim3(D_INNER/256, BB, NCHUNK),256,0,stream>>>(
            dtbb, ucb, xdbl, A_log + (size_t)i*D_INNER*D_STATE, xzb,
            Dd + (size_t)i*D_INNER, hstart, ysb);
        // xcur = ys @ out_w^T + xin (2048x1024 K=2048), fp32 + bf16 copy.
        gemm_op<<<512,256,0,stream>>>(
            ysb, woutb + (size_t)i*1024*2048, xcur, BT, 1024, D_INNER,
            xin, xinb, 8, 8, 2);
    }
    layernorm_k<<<BT,256,0,stream>>>(xcur, nw, nb, out);
}

// Round 16
// 681.239 us; speedup vs baseline: 1.0712x; 1.0712x over previous
//
#include <hip/hip_runtime.h>
#include <hip/hip_bf16.h>

#define N_LAYERS 4
#define D_MODEL  1024
#define D_INNER  2048
#define D_STATE  16
#define D_CONV   4
#define DT_RANK  64
#define BB       2
#define TT       1024
#define BT       (BB*TT)   // 2048 rows (b*T)

#define NCHUNK 32
#define SCTC   (TT/NCHUNK)   // 32 timesteps per chunk
#define TB     8             // scan load-batch depth

#define XP_KS  8             // x_proj K-split factor

typedef unsigned short ushort_t;
typedef __attribute__((ext_vector_type(8))) short short8;
typedef __attribute__((ext_vector_type(8))) unsigned short ushort8_t;
typedef __attribute__((ext_vector_type(4))) float f32x4;

__device__ __forceinline__ float sigmoidf_(float x){ return 1.f/(1.f+__expf(-x)); }
__device__ __forceinline__ float siluf_(float x){ return x*sigmoidf_(x); }
__device__ __forceinline__ float softplusf_(float x){ return fmaxf(x,0.f) + log1pf(__expf(-fabsf(x))); }
__device__ __forceinline__ ushort_t f2b(float f){
    unsigned int x = __builtin_bit_cast(unsigned int, f);
    unsigned int r = (x + 0x7fffu + ((x>>16)&1u)) >> 16;   // RNE
    return (ushort_t)r;
}
__device__ __forceinline__ float b2f(ushort_t u){
    unsigned int x = ((unsigned int)u) << 16;
    return __builtin_bit_cast(float, x);
}

#define GLOAD(g, l) __builtin_amdgcn_global_load_lds( \
    (const __attribute__((address_space(1))) void*)(g), \
    (__attribute__((address_space(3))) void*)(l), 16, 0, 0)

// One-shot conversion: x, in_w(all), out_w(all), dtp_w(all) -> bf16.
// 8 floats/thread: 2x float4 read, one 16B ushort8 store.
__global__ __launch_bounds__(256) void f2ball_k(
    const float* __restrict__ x, const float* __restrict__ in_w,
    const float* __restrict__ out_w, const float* __restrict__ dtp_w,
    ushort_t* __restrict__ xinb, ushort_t* __restrict__ winb,
    ushort_t* __restrict__ woutb, ushort_t* __restrict__ dtpb)
{
    const int n0 = (BT*1024)/8;
    const int n1 = (N_LAYERS*4096*1024)/8;
    const int n2 = (N_LAYERS*1024*2048)/8;
    int i = blockIdx.x*256 + threadIdx.x;
    const float4* src; ushort8_t* dst; int j;
    if (i < n0){ src=(const float4*)x; dst=(ushort8_t*)xinb; j=i; }
    else if (i < n0+n1){ src=(const float4*)in_w; dst=(ushort8_t*)winb; j=i-n0; }
    else if (i < n0+n1+n2){ src=(const float4*)out_w; dst=(ushort8_t*)woutb; j=i-n0-n1; }
    else { src=(const float4*)dtp_w; dst=(ushort8_t*)dtpb; j=i-n0-n1-n2; }
    float4 v0 = src[2*j], v1 = src[2*j+1];
    ushort8_t o;
    o[0]=f2b(v0.x); o[1]=f2b(v0.y); o[2]=f2b(v0.z); o[3]=f2b(v0.w);
    o[4]=f2b(v1.x); o[5]=f2b(v1.y); o[6]=f2b(v1.z); o[7]=f2b(v1.w);
    dst[j] = o;
}

// in_proj GEMM: outb[M][N](bf16) = A[M][K] @ W[N][K]^T. 128x128 tile, BK=32,
// 512 thr = 8 waves (2x4), wave = 64x32 via 4x2 frags. Depth-3 pipeline,
// 4 LDS buffers, vmcnt(4), setprio around MFMA. XCD rect swizzle.
__global__ __launch_bounds__(512) void gemm_ip(
    const ushort_t* __restrict__ A, const ushort_t* __restrict__ W,
    int M, int N, int K, ushort_t* __restrict__ outb,
    int RM, int RN, int XN)
{
    __shared__ ushort_t As[4][128*32];
    __shared__ ushort_t Ws[4][128*32];
    const int tid  = threadIdx.x;
    const int lane = tid & 63;
    const int wv   = tid >> 6;
    const int wm0  = (wv>>2)*64, wn0 = (wv&3)*32;

    const int bid = blockIdx.x;
    const int xcd = bid & 7, bi = bid >> 3;
    const int xm = xcd / XN, xn = xcd - xm*XN;
    const int m0 = (xm*RM + bi/RN)*128;
    const int n0 = (xn*RN + bi - (bi/RN)*RN)*128;

    const int r0 = tid>>2, ch = tid&3;

    f32x4 acc[4][2];
    #pragma unroll
    for (int i=0;i<4;++i)
        #pragma unroll
        for (int j=0;j<2;++j) acc[i][j] = (f32x4){0.f,0.f,0.f,0.f};

    const int row_a = lane & 15, kc = (lane>>4)*8;
    const ushort_t* gA = A + (size_t)(m0+r0)*K + ch*8;
    const ushort_t* gW = W + (size_t)(n0+r0)*K + ch*8;

#define STAGE(KT, BUF) { \
    GLOAD(gA + (KT)*32, (char*)&As[BUF][0] + tid*16); \
    GLOAD(gW + (KT)*32, (char*)&Ws[BUF][0] + tid*16); }

#define COMPUTE(BUF) { \
    short8 af[4], bf[2]; \
    _Pragma("unroll") \
    for (int i=0;i<4;++i) af[i] = *(const short8*)&As[BUF][(wm0 + i*16 + row_a)*32 + kc]; \
    _Pragma("unroll") \
    for (int j=0;j<2;++j) bf[j] = *(const short8*)&Ws[BUF][(wn0 + j*16 + row_a)*32 + kc]; \
    __builtin_amdgcn_s_setprio(1); \
    _Pragma("unroll") \
    for (int i=0;i<4;++i) \
        _Pragma("unroll") \
        for (int j=0;j<2;++j) \
            acc[i][j] = __builtin_amdgcn_mfma_f32_16x16x32_bf16(af[i], bf[j], acc[i][j], 0,0,0); \
    __builtin_amdgcn_s_setprio(0); }

    const int nt = K >> 5;
    STAGE(0, 0); STAGE(1, 1); STAGE(2, 2);
    for (int t = 0; t < nt-3; ++t){
        asm volatile("s_waitcnt vmcnt(4)" ::: "memory");
        asm volatile("s_barrier" ::: "memory");
        STAGE(t+3, (t+3)&3);
        COMPUTE(t&3);
    }
    asm volatile("s_waitcnt vmcnt(4)" ::: "memory");
    asm volatile("s_barrier" ::: "memory");
    COMPUTE((nt-3)&3);
    asm volatile("s_waitcnt vmcnt(2)" ::: "memory");
    asm volatile("s_barrier" ::: "memory");
    COMPUTE((nt-2)&3);
    asm volatile("s_waitcnt vmcnt(0)" ::: "memory");
    asm volatile("s_barrier" ::: "memory");
    COMPUTE((nt-1)&3);
#undef STAGE
#undef COMPUTE

    const int crow = (lane>>4)*4, ccol = lane & 15;
    #pragma unroll
    for (int i=0;i<4;++i){
        #pragma unroll
        for (int j=0;j<2;++j){
            #pragma unroll
            for (int r=0;r<4;++r){
                int m = m0 + wm0 + i*16 + crow + r;
                int n = n0 + wn0 + j*16 + ccol;
                outb[(size_t)m*N + n] = f2b(acc[i][j][r]);
            }
        }
    }
}

// out_proj GEMM: C = ys @ W^T + res (fp32), bf16 copy to outb. 64x64 tile,
// 4 waves of 32x32. Step-paired: 6 LDS buffers, 2 BK=32 steps per barrier,
// vmcnt(4), setprio. XCD rect swizzle.
__global__ __launch_bounds__(256) void gemm_op(
    const ushort_t* __restrict__ A, const ushort_t* __restrict__ W,
    float* __restrict__ C, int M, int N, int K,
    const float* __restrict__ res, ushort_t* __restrict__ outb,
    int RM, int RN, int XN)
{
    __shared__ ushort_t As[6][64*32];
    __shared__ ushort_t Ws[6][64*32];
    const int tid  = threadIdx.x;
    const int lane = tid & 63;
    const int wv   = tid >> 6;
    const int wm0  = (wv>>1)*32, wn0 = (wv&1)*32;

    const int bid = blockIdx.x;
    const int xcd = bid & 7, bi = bid >> 3;
    const int xm = xcd / XN, xn = xcd - xm*XN;
    const int m0 = (xm*RM + bi/RN)*64;
    const int n0 = (xn*RN + bi - (bi/RN)*RN)*64;

    const int r0 = tid>>2, ch = tid&3;

    f32x4 acc[2][2];
    #pragma unroll
    for (int i=0;i<2;++i)
        #pragma unroll
        for (int j=0;j<2;++j) acc[i][j] = (f32x4){0.f,0.f,0.f,0.f};

    const int row_a = lane & 15, kc = (lane>>4)*8;
    const ushort_t* gA = A + (size_t)(m0+r0)*K + ch*8;
    const ushort_t* gW = W + (size_t)(n0+r0)*K + ch*8;

#define STAGE(KT, BUF) { \
    GLOAD(gA + (KT)*32, (char*)&As[BUF][0] + tid*16); \
    GLOAD(gW + (KT)*32, (char*)&Ws[BUF][0] + tid*16); }

#define COMPUTE(BUF) { \
    short8 af[2], bf[2]; \
    _Pragma("unroll") \
    for (int i=0;i<2;++i) af[i] = *(const short8*)&As[BUF][(wm0 + i*16 + row_a)*32 + kc]; \
    _Pragma("unroll") \
    for (int j=0;j<2;++j) bf[j] = *(const short8*)&Ws[BUF][(wn0 + j*16 + row_a)*32 + kc]; \
    _Pragma("unroll") \
    for (int i=0;i<2;++i) \
        _Pragma("unroll") \
        for (int j=0;j<2;++j) \
            acc[i][j] = __builtin_amdgcn_mfma_f32_16x16x32_bf16(af[i], bf[j], acc[i][j], 0,0,0); }

    const int np = K >> 6;            // step pairs (K=2048 -> 32)
    STAGE(0, 0); STAGE(1, 1);
    STAGE(2, 2); STAGE(3, 3);
    for (int p = 0; p < np-2; ++p){
        const int bA = (p%3)*2, bS = ((p+2)%3)*2;
        asm volatile("s_waitcnt vmcnt(4)" ::: "memory");
        asm volatile("s_barrier" ::: "memory");
        STAGE(2*p+4, bS); STAGE(2*p+5, bS+1);
        __builtin_amdgcn_s_setprio(1);
        COMPUTE(bA); COMPUTE(bA+1);
        __builtin_amdgcn_s_setprio(0);
    }
    {
        const int bA = ((np-2)%3)*2;
        asm volatile("s_waitcnt vmcnt(4)" ::: "memory");
        asm volatile("s_barrier" ::: "memory");
        COMPUTE(bA); COMPUTE(bA+1);
    }
    {
        const int bA = ((np-1)%3)*2;
        asm volatile("s_waitcnt vmcnt(0)" ::: "memory");
        asm volatile("s_barrier" ::: "memory");
        COMPUTE(bA); COMPUTE(bA+1);
    }
#undef STAGE
#undef COMPUTE

    const int crow = (lane>>4)*4, ccol = lane & 15;
    #pragma unroll
    for (int i=0;i<2;++i){
        #pragma unroll
        for (int j=0;j<2;++j){
            #pragma unroll
            for (int r=0;r<4;++r){
                int m = m0 + wm0 + i*16 + crow + r;
                int n = n0 + wn0 + j*16 + ccol;
                float v = acc[i][j][r] + res[(size_t)m*N + n];
                C[(size_t)m*N + n] = v;
                outb[(size_t)m*N + n] = f2b(v);
            }
        }
    }
}

// dt_proj bf16 MFMA: dtb[M][N](bf16) = softplus(A[M][64] @ W[N][64]^T + bias).
__global__ __launch_bounds__(256) void dt_mfma(
    const ushort_t* __restrict__ A, const ushort_t* __restrict__ W,
    const float* __restrict__ bias, ushort_t* __restrict__ dtb, int N)
{
    __shared__ ushort_t As[2][64*32];
    __shared__ ushort_t Ws[2][64*32];
    const int tid = threadIdx.x, lane = tid&63, wv = tid>>6;
    const int wm0 = (wv>>1)*32, wn0 = (wv&1)*32;
    const int m0 = blockIdx.y*64, n0 = blockIdx.x*64;
    const int r0 = tid>>2, ch = tid&3;
    const ushort_t* gA = A + (size_t)(m0+r0)*64 + ch*8;
    const ushort_t* gW = W + (size_t)(n0+r0)*64 + ch*8;
    GLOAD(gA,      (char*)&As[0][0] + tid*16);
    GLOAD(gW,      (char*)&Ws[0][0] + tid*16);
    GLOAD(gA + 32, (char*)&As[1][0] + tid*16);
    GLOAD(gW + 32, (char*)&Ws[1][0] + tid*16);

    f32x4 acc[2][2];
    #pragma unroll
    for (int i=0;i<2;++i)
        #pragma unroll
        for (int j=0;j<2;++j) acc[i][j] = (f32x4){0.f,0.f,0.f,0.f};

    asm volatile("s_waitcnt vmcnt(0)" ::: "memory");
    asm volatile("s_barrier" ::: "memory");
    const int row_a = lane&15, kc = (lane>>4)*8;
    #pragma unroll
    for (int buf=0; buf<2; ++buf){
        short8 af[2], bf[2];
        #pragma unroll
        for (int i=0;i<2;++i) af[i] = *(const short8*)&As[buf][(wm0 + i*16 + row_a)*32 + kc];
        #pragma unroll
        for (int j=0;j<2;++j) bf[j] = *(const short8*)&Ws[buf][(wn0 + j*16 + row_a)*32 + kc];
        #pragma unroll
        for (int i=0;i<2;++i)
            #pragma unroll
            for (int j=0;j<2;++j)
                acc[i][j] = __builtin_amdgcn_mfma_f32_16x16x32_bf16(af[i], bf[j], acc[i][j], 0,0,0);
    }

    const int crow = (lane>>4)*4, ccol = lane & 15;
    #pragma unroll
    for (int i=0;i<2;++i){
        #pragma unroll
        for (int j=0;j<2;++j){
            #pragma unroll
            for (int r=0;r<4;++r){
                int m = m0 + wm0 + i*16 + crow + r;
                int n = n0 + wn0 + j*16 + ccol;
                float v = softplusf_(acc[i][j][r] + bias[n]);
                dtb[(size_t)m*N + n] = f2b(v);
            }
        }
    }
}

// Depthwise causal conv (K=4) + bias + SiLU: bf16 in (xzb u-half), bf16 out.
// 8 channels/thread, ushort8 loads/store. One block = one bt row.
__global__ __launch_bounds__(256) void conv_silu_k(
    const ushort_t* __restrict__ xzb, const float* __restrict__ cw,
    const float* __restrict__ cb, ushort_t* __restrict__ ucb)
{
    int idx = blockIdx.x*256 + threadIdx.x;   // over BT*256
    int d8 = (idx & 255) << 3;                // channel base
    int bt = idx >> 8;
    int t  = bt & (TT-1);
    ushort8_t z8 = (ushort8_t)0;
    ushort8_t r0 = (t>=3) ? *(const ushort8_t*)(xzb + (size_t)(bt-3)*4096 + d8) : z8;
    ushort8_t r1 = (t>=2) ? *(const ushort8_t*)(xzb + (size_t)(bt-2)*4096 + d8) : z8;
    ushort8_t r2 = (t>=1) ? *(const ushort8_t*)(xzb + (size_t)(bt-1)*4096 + d8) : z8;
    ushort8_t r3 = *(const ushort8_t*)(xzb + (size_t)bt*4096 + d8);
    ushort8_t o;
    #pragma unroll
    for (int j=0;j<8;++j){
        float4 w4 = *(const float4*)(cw + (size_t)(d8+j)*4);
        float a = cb[d8+j];
        a = fmaf(b2f(r0[j]), w4.x, a);
        a = fmaf(b2f(r1[j]), w4.y, a);
        a = fmaf(b2f(r2[j]), w4.z, a);
        a = fmaf(b2f(r3[j]), w4.w, a);
        o[j] = f2b(siluf_(a));
    }
    *(ushort8_t*)(ucb + (size_t)bt*D_INNER + d8) = o;
}

// Split-K fp32 GEMM for x_proj (A in bf16 = ucb): grid (N/64, M/64, XP_KS).
__global__ __launch_bounds__(256) void gemm_tn_sk(
    const ushort_t* __restrict__ A, int lda,
    const float* __restrict__ W, int ldw,
    float* __restrict__ P, int M, int N, int K)
{
    __shared__ float As[16][68];
    __shared__ float Ws[16][68];
    const int tid = threadIdx.x;
    const int tx = tid & 15, ty = tid >> 4;
    const int m0 = blockIdx.y * 64, n0 = blockIdx.x * 64;
    const int kbase = blockIdx.z * (K/XP_KS);
    const int lr = tid >> 2;
    const int lk = (tid & 3) << 2;
    float acc[4][4] = {{0.f}};

    for (int kk = 0; kk < K/XP_KS; kk += 16) {
        int k0 = kbase + kk;
        ushort4 av4 = *(const ushort4*)(A + (size_t)(m0+lr)*lda + k0 + lk);
        float4 wv = make_float4(0.f,0.f,0.f,0.f);
        if (n0 + lr < N) wv = *(const float4*)(W + (size_t)(n0+lr)*ldw + k0 + lk);
        __syncthreads();
        As[lk+0][lr]=b2f(av4.x); As[lk+1][lr]=b2f(av4.y);
        As[lk+2][lr]=b2f(av4.z); As[lk+3][lr]=b2f(av4.w);
        Ws[lk+0][lr]=wv.x; Ws[lk+1][lr]=wv.y; Ws[lk+2][lr]=wv.z; Ws[lk+3][lr]=wv.w;
        __syncthreads();
        #pragma unroll
        for (int k = 0; k < 16; ++k) {
            float4 a = *(const float4*)&As[k][ty<<2];
            float4 b = *(const float4*)&Ws[k][tx<<2];
            float a4[4] = {a.x,a.y,a.z,a.w};
            float b4[4] = {b.x,b.y,b.z,b.w};
            #pragma unroll
            for (int i=0;i<4;++i)
                #pragma unroll
                for (int j=0;j<4;++j)
                    acc[i][j] = fmaf(a4[i], b4[j], acc[i][j]);
        }
    }

    float* Pz = P + (size_t)blockIdx.z * M * 96;
    #pragma unroll
    for (int i=0;i<4;++i){
        int m = m0 + (ty<<2) + i;
        #pragma unroll
        for (int j=0;j<4;++j){
            int n = n0 + (tx<<2) + j;
            if (n < N) Pz[(size_t)m*96 + n] = acc[i][j];
        }
    }
}

// xdbl[g] = sum_ks P[ks][g]; also emit bf16 dt_r (cols<64) to dtrb[M][64].
__global__ __launch_bounds__(256) void sk_reduce(
    const float* __restrict__ P, float* __restrict__ outp,
    ushort_t* __restrict__ dtrb, int MN)
{
    int g = blockIdx.x*256 + threadIdx.x;
    float s = 0.f;
    #pragma unroll
    for (int ks=0; ks<XP_KS; ++ks) s += P[(size_t)ks*MN + g];
    outp[g] = s;
    int m = g / 96, c = g - m*96;
    if (c < 64) dtrb[(size_t)m*64 + c] = f2b(s);
}

// ---- Chunked selective scan (3 phases), bf16 dt/u, TB-step load batching. ----

__global__ __launch_bounds__(256) void scan_p1(
    const ushort_t* __restrict__ dt, const ushort_t* __restrict__ uc,
    const float* __restrict__ xdbl, const float* __restrict__ A_log,
    float* __restrict__ hpart, float* __restrict__ hdecay)
{
    const int tid = threadIdx.x;
    const int d = blockIdx.x*256 + tid;
    const int b = blockIdx.y;
    const int k = blockIdx.z;
    const int t0 = k*SCTC;
    float A[16];
    #pragma unroll
    for (int q=0;q<4;++q){
        float4 v = *(const float4*)(A_log + (size_t)d*16 + q*4);
        A[q*4+0]=-__expf(v.x); A[q*4+1]=-__expf(v.y);
        A[q*4+2]=-__expf(v.z); A[q*4+3]=-__expf(v.w);
    }
    float h[16];
    #pragma unroll
    for (int s=0;s<16;++s) h[s]=0.f;
    float sumdt = 0.f;
    const ushort_t* dtp = dt + ((size_t)b*TT + t0)*D_INNER + d;
    const ushort_t* ucp = uc + ((size_t)b*TT + t0)*D_INNER + d;
    const float* bcp = xdbl + ((size_t)b*TT + t0)*96 + 64;
    #pragma unroll
    for (int tb=0; tb<SCTC; tb+=TB){
        float dtv[TB], ur[TB];
        #pragma unroll
        for (int j=0;j<TB;++j){
            dtv[j] = b2f(dtp[(size_t)(tb+j)*D_INNER]);
            ur[j]  = b2f(ucp[(size_t)(tb+j)*D_INNER]);
        }
        #pragma unroll
        for (int j=0;j<TB;++j){
            const float* bc = bcp + (size_t)(tb+j)*96;
            float du = dtv[j]*ur[j];
            sumdt += dtv[j];
            #pragma unroll
            for (int s=0;s<16;++s)
                h[s] = fmaf(__expf(dtv[j]*A[s]), h[s], du*bc[s]);
        }
    }
    size_t base = ((size_t)(k*BB+b)*D_INNER + d)*16;
    float4* hp = (float4*)(hpart + base);
    float4* hd = (float4*)(hdecay + base);
    #pragma unroll
    for (int q=0;q<4;++q){
        hp[q] = make_float4(h[q*4],h[q*4+1],h[q*4+2],h[q*4+3]);
        hd[q] = make_float4(__expf(sumdt*A[q*4+0]),__expf(sumdt*A[q*4+1]),
                            __expf(sumdt*A[q*4+2]),__expf(sumdt*A[q*4+3]));
    }
}

__global__ __launch_bounds__(256) void scan_fix(
    const float* __restrict__ hpart, const float* __restrict__ hdecay,
    float* __restrict__ hstart)
{
    int g = blockIdx.x*256 + threadIdx.x;
    float h = 0.f;
    #pragma unroll
    for (int k=0;k<NCHUNK;++k){
        size_t idx = (size_t)k*(BB*D_INNER*16) + g;
        hstart[idx] = h;
        h = fmaf(hdecay[idx], h, hpart[idx]);
    }
}

__global__ __launch_bounds__(256) void scan_p3(
    const ushort_t* __restrict__ dt, const ushort_t* __restrict__ uc,
    const float* __restrict__ xdbl, const float* __restrict__ A_log,
    const ushort_t* __restrict__ xzb, const float* __restrict__ Dd,
    const float* __restrict__ hstart, ushort_t* __restrict__ ysb)
{
    const int tid = threadIdx.x;
    const int d = blockIdx.x*256 + tid;
    const int b = blockIdx.y;
    const int k = blockIdx.z;
    const int t0 = k*SCTC;
    float A[16];
    #pragma unroll
    for (int q=0;q<4;++q){
        float4 v = *(const float4*)(A_log + (size_t)d*16 + q*4);
        A[q*4+0]=-__expf(v.x); A[q*4+1]=-__expf(v.y);
        A[q*4+2]=-__expf(v.z); A[q*4+3]=-__expf(v.w);
    }
    float h[16];
    {
        const float4* hs = (const float4*)(hstart + ((size_t)(k*BB+b)*D_INNER + d)*16);
        #pragma unroll
        for (int q=0;q<4;++q){
            float4 v = hs[q];
            h[q*4+0]=v.x; h[q*4+1]=v.y; h[q*4+2]=v.z; h[q*4+3]=v.w;
        }
    }
    const float Ddc = Dd[d];
    const ushort_t* dtp = dt + ((size_t)b*TT + t0)*D_INNER + d;
    const ushort_t* ucp = uc + ((size_t)b*TT + t0)*D_INNER + d;
    const ushort_t* zp  = xzb + ((size_t)b*TT + t0)*4096 + 2048 + d;
    const float* bcp = xdbl + ((size_t)b*TT + t0)*96 + 64;
    ushort_t* yp = ysb + ((size_t)b*TT + t0)*D_INNER + d;
    #pragma unroll
    for (int tb=0; tb<SCTC; tb+=TB){
        float dtv[TB], ur[TB], zr[TB];
        #pragma unroll
        for (int j=0;j<TB;++j){
            dtv[j] = b2f(dtp[(size_t)(tb+j)*D_INNER]);
            ur[j]  = b2f(ucp[(size_t)(tb+j)*D_INNER]);
            zr[j]  = b2f(zp [(size_t)(tb+j)*4096]);
        }
        #pragma unroll
        for (int j=0;j<TB;++j){
            const float* bc = bcp + (size_t)(tb+j)*96;
            float du = dtv[j]*ur[j];
            float y0=0.f,y1=0.f,y2=0.f,y3=0.f;
            #pragma unroll
            for (int q=0;q<4;++q){
                h[q*4+0] = fmaf(__expf(dtv[j]*A[q*4+0]), h[q*4+0], du*bc[q*4+0]);
                h[q*4+1] = fmaf(__expf(dtv[j]*A[q*4+1]), h[q*4+1], du*bc[q*4+1]);
                h[q*4+2] = fmaf(__expf(dtv[j]*A[q*4+2]), h[q*4+2], du*bc[q*4+2]);
                h[q*4+3] = fmaf(__expf(dtv[j]*A[q*4+3]), h[q*4+3], du*bc[q*4+3]);
            }
            #pragma unroll
            for (int q=0;q<4;++q){
                y0 = fmaf(h[q*4+0], bc[16+q*4+0], y0);
                y1 = fmaf(h[q*4+1], bc[16+q*4+1], y1);
                y2 = fmaf(h[q*4+2], bc[16+q*4+2], y2);
                y3 = fmaf(h[q*4+3], bc[16+q*4+3], y3);
            }
            float y = (y0+y1)+(y2+y3);
            float yv = (y + ur[j]*Ddc) * siluf_(zr[j]);
            yp[(size_t)(tb+j)*D_INNER] = f2b(yv);
        }
    }
}

__global__ __launch_bounds__(256) void layernorm_k(
    const float* __restrict__ X, const float* __restrict__ w,
    const float* __restrict__ b, float* __restrict__ out)
{
    int row = blockIdx.x;
    int tid = threadIdx.x;
    const float* xr = X + (size_t)row*D_MODEL;
    float4 v = *(const float4*)(xr + tid*4);
    float s  = v.x+v.y+v.z+v.w;
    float ss = fmaf(v.x,v.x, fmaf(v.y,v.y, fmaf(v.z,v.z, v.w*v.w)));
    #pragma unroll
    for (int off=32; off>0; off>>=1){
        s  += __shfl_down(s, off, 64);
        ss += __shfl_down(ss, off, 64);
    }
    __shared__ float red[8];
    int wid = tid>>6, lane = tid&63;
    if (lane==0){ red[wid]=s; red[4+wid]=ss; }
    __syncthreads();
    if (tid==0){
        float S  = red[0]+red[1]+red[2]+red[3];
        float SS = red[4]+red[5]+red[6]+red[7];
        float mu = S*(1.f/D_MODEL);
        float var = SS*(1.f/D_MODEL) - mu*mu;
        red[0]=mu; red[1]=rsqrtf(var + 1e-5f);
    }
    __syncthreads();
    float mu=red[0], rs=red[1];
    float4 wv = *(const float4*)(w + tid*4);
    float4 bv = *(const float4*)(b + tid*4);
    float4 o;
    o.x = fmaf((v.x-mu)*rs, wv.x, bv.x);
    o.y = fmaf((v.y-mu)*rs, wv.y, bv.y);
    o.z = fmaf((v.z-mu)*rs, wv.z, bv.z);
    o.w = fmaf((v.w-mu)*rs, wv.w, bv.w);
    *(float4*)(out + (size_t)row*D_MODEL + tid*4) = o;
}

extern "C" void kernel_launch(void* const* d_in, const int* in_sizes, int n_in,
                              void* d_out, int out_size, void* d_ws, size_t ws_size,
                              hipStream_t stream) {
    (void)in_sizes; (void)n_in; (void)out_size; (void)ws_size;
    const float* x      = (const float*)d_in[0];
    const float* in_w   = (const float*)d_in[1];
    const float* conv_w = (const float*)d_in[2];
    const float* conv_b = (const float*)d_in[3];
    const float* xp_w   = (const float*)d_in[4];
    const float* dtp_w  = (const float*)d_in[5];
    const float* dtp_b  = (const float*)d_in[6];
    const float* A_log  = (const float*)d_in[7];
    const float* Dd     = (const float*)d_in[8];
    const float* out_w  = (const float*)d_in[9];
    const float* nw     = (const float*)d_in[10];
    const float* nb     = (const float*)d_in[11];
    float* out = (float*)d_out;

    char* p = (char*)d_ws;
    ushort_t* xzb  = (ushort_t*)p; p += (size_t)BT*4096*2;     // 16 MB
    ushort_t* ucb  = (ushort_t*)p; p += (size_t)BT*2048*2;     // 8 MB
    float* xdbl    = (float*)p;  p += (size_t)BT*96*4;         // 768 KB
    ushort_t* dtrb = (ushort_t*)p; p += (size_t)BT*64*2;       // 256 KB
    ushort_t* dtbb = (ushort_t*)p; p += (size_t)BT*2048*2;     // 8 MB
    float* xcur    = (float*)p;  p += (size_t)BT*1024*4;       // 8 MB
    ushort_t* xinb = (ushort_t*)p; p += (size_t)BT*1024*2;     // 4 MB
    ushort_t* ysb  = (ushort_t*)p; p += (size_t)BT*2048*2;     // 8 MB
    ushort_t* winb = (ushort_t*)p; p += (size_t)N_LAYERS*4096*1024*2;  // 32 MB
    ushort_t* woutb= (ushort_t*)p; p += (size_t)N_LAYERS*1024*2048*2;  // 16 MB
    ushort_t* dtpb = (ushort_t*)p; p += (size_t)N_LAYERS*2048*64*2;    // 1 MB
    float* hpart   = (float*)p;  p += (size_t)NCHUNK*BB*D_INNER*16*4;  // 8 MB
    float* hdecay  = (float*)p;  p += (size_t)NCHUNK*BB*D_INNER*16*4;  // 8 MB
    float* hstart  = (float*)p;  p += (size_t)NCHUNK*BB*D_INNER*16*4;  // 8 MB
    // pbuf (x_proj split-K partials, 6.3 MB) aliases hpart: consumed by
    // sk_reduce before scan_p1 writes hpart.
    float* pbuf    = hpart;

    // One-time conversions: x + all layers' weights, single launch.
    f2ball_k<<<(BT*1024 + N_LAYERS*(4096*1024 + 1024*2048 + 2048*64))/2048,
               256,0,stream>>>(x, in_w, out_w, dtp_w, xinb, winb, woutb, dtpb);

    for (int i = 0; i < N_LAYERS; ++i){
        const float* xin = (i==0) ? x : xcur;
        const float* cw = conv_w + (size_t)i*D_INNER*D_CONV;
        const float* cb = conv_b + (size_t)i*D_INNER;
        // xz = xin @ in_w^T (2048x4096 K=1024) -> bf16 xzb.
        gemm_ip<<<512,512,0,stream>>>(
            xinb, winb + (size_t)i*4096*1024, BT, 4096, D_MODEL, xzb, 8, 8, 4);
        // uc = silu(causal_conv(u) + cb) -> bf16, vectorized 8 ch/thread
        conv_silu_k<<<BT,256,0,stream>>>(xzb, cw, cb, ucb);
        // x_dbl = uc @ xp_w^T (2048 x 96 x K=2048), fp32 split-K, bf16 A
        gemm_tn_sk<<<dim3(2,32,XP_KS),256,0,stream>>>(
            ucb, D_INNER, xp_w + (size_t)i*96*D_INNER, D_INNER,
            pbuf, BT, 96, D_INNER);
        sk_reduce<<<(BT*96)/256,256,0,stream>>>(pbuf, xdbl, dtrb, BT*96);
        // dt = softplus(dt_r @ dtp_w^T + dtp_b) -> bf16, MFMA (K=64)
        dt_mfma<<<dim3(D_INNER/64, BT/64),256,0,stream>>>(
            dtrb, dtpb + (size_t)i*2048*64, dtp_b + (size_t)i*D_INNER, dtbb, D_INNER);
        // chunked selective scan (batched loads) + fused (y+u*D)*silu(z) -> bf16
        scan_p1<<<dim3(D_INNER/256, BB, NCHUNK),256,0,stream>>>(
            dtbb, ucb, xdbl, A_log + (size_t)i*D_INNER*D_STATE, hpart, hdecay);
        scan_fix<<<(BB*D_INNER*16)/256,256,0,stream>>>(hpart, hdecay, hstart);
        scan_p3<<<dim3(D_INNER/256, BB, NCHUNK),256,0,stream>>>(
            dtbb, ucb, xdbl, A_log + (size_t)i*D_INNER*D_STATE, xzb,
            Dd + (size_t)i*D_INNER, hstart, ysb);
        // xcur = ys @ out_w^T + xin (2048x1024 K=2048), fp32 + bf16 copy.
        gemm_op<<<512,256,0,stream>>>(
            ysb, woutb + (size_t)i*1024*2048, xcur, BT, 1024, D_INNER,
            xin, xinb, 8, 8, 2);
    }
    layernorm_k<<<BT,256,0,stream>>>(xcur, nw, nb, out);
}